// Round 2
// baseline (11042.972 us; speedup 1.0000x reference)
//
#include <hip/hip_runtime.h>
#include <hip/hip_bf16.h>
#include <math.h>

#define E 512
#define H_HEADS 8
#define DH 64
#define NLAYER 6
#define DFF 2048
#define SEQ 2048      // T*V
#define NB 2          // batch
#define M_TOK (NB*SEQ) // 4096 rows

// ---------------- embedding: x = code_emb[idx] + stage + time_pos + joint_pos ----------------
__global__ __launch_bounds__(256) void embed_kernel(
    const int* __restrict__ idx, const float* __restrict__ ce,
    const float* __restrict__ se, const float* __restrict__ tp,
    const float* __restrict__ jp, float* __restrict__ x)
{
    int i = blockIdx.x * 256 + threadIdx.x;   // float4 index, total 524288
    int e4 = i & 127;                          // E/4 = 128
    int row = i >> 7;                          // 0..4095  = b*2048 + t*32 + v
    int v = row & 31;
    int t = (row >> 5) & 63;
    int code = idx[row];
    const float4* ce4 = (const float4*)ce;
    const float4* se4 = (const float4*)se;
    const float4* tp4 = (const float4*)tp;
    const float4* jp4 = (const float4*)jp;
    float4 a = ce4[code * 128 + e4];
    float4 b = se4[e4];
    float4 c = tp4[t * 128 + e4];
    float4 d = jp4[v * 128 + e4];
    float4 o;
    o.x = a.x + b.x + c.x + d.x;
    o.y = a.y + b.y + c.y + d.y;
    o.z = a.z + b.z + c.z + d.z;
    o.w = a.w + b.w + c.w + d.w;
    ((float4*)x)[i] = o;
}

// ---------------- LayerNorm: one wave per row of 512 ----------------
__global__ __launch_bounds__(256) void ln_kernel(
    const float* __restrict__ x, float* __restrict__ y,
    const float* __restrict__ g, const float* __restrict__ b)
{
    int wave = threadIdx.x >> 6;
    int lane = threadIdx.x & 63;
    int row = blockIdx.x * 4 + wave;
    const float4* xr = (const float4*)(x + (size_t)row * E);
    float4 v0 = xr[lane];
    float4 v1 = xr[lane + 64];
    float s  = v0.x + v0.y + v0.z + v0.w + v1.x + v1.y + v1.z + v1.w;
    float ss = v0.x*v0.x + v0.y*v0.y + v0.z*v0.z + v0.w*v0.w
             + v1.x*v1.x + v1.y*v1.y + v1.z*v1.z + v1.w*v1.w;
    #pragma unroll
    for (int off = 32; off; off >>= 1) {
        s  += __shfl_xor(s, off, 64);
        ss += __shfl_xor(ss, off, 64);
    }
    float mu = s * (1.f / E);
    float var = ss * (1.f / E) - mu * mu;
    float rs = rsqrtf(var + 1e-5f);
    const float4* g4 = (const float4*)g;
    const float4* b4 = (const float4*)b;
    float4* yr = (float4*)(y + (size_t)row * E);
    float4 gg = g4[lane], bb = b4[lane];
    float4 o;
    o.x = (v0.x - mu) * rs * gg.x + bb.x;
    o.y = (v0.y - mu) * rs * gg.y + bb.y;
    o.z = (v0.z - mu) * rs * gg.z + bb.z;
    o.w = (v0.w - mu) * rs * gg.w + bb.w;
    yr[lane] = o;
    gg = g4[lane + 64]; bb = b4[lane + 64];
    o.x = (v1.x - mu) * rs * gg.x + bb.x;
    o.y = (v1.y - mu) * rs * gg.y + bb.y;
    o.z = (v1.z - mu) * rs * gg.z + bb.z;
    o.w = (v1.w - mu) * rs * gg.w + bb.w;
    yr[lane + 64] = o;
}

// ---------------- GEMM: out[M,N] = A[M,K] @ W[N,K]^T + bias (+res / gelu) ----------------
// MODE 0: plain   MODE 1: + res (residual, res may alias out)   MODE 2: gelu(.)
template<int MODE>
__global__ __launch_bounds__(256) void gemm_kernel(
    const float* __restrict__ A, const float* __restrict__ W,
    const float* __restrict__ bias, const float* __restrict__ res,
    float* __restrict__ out, int N, int K)
{
    __shared__ __align__(16) float As[16][68];
    __shared__ __align__(16) float Ws[16][68];
    int nb = N >> 6;
    int bx = blockIdx.x % nb;
    int by = blockIdx.x / nb;
    int tid = threadIdx.x;
    int tx = tid & 15, ty = tid >> 4;
    float acc[4][4] = {};
    const float* Ab = A + (size_t)(by * 64) * K;
    const float* Wb = W + (size_t)(bx * 64) * K;
    for (int k0 = 0; k0 < K; k0 += 16) {
        __syncthreads();
        #pragma unroll
        for (int p = 0; p < 4; ++p) {
            int idx = p * 256 + tid;
            int kk = idx & 15, m = idx >> 4;
            As[kk][m] = Ab[(size_t)m * K + k0 + kk];
            Ws[kk][m] = Wb[(size_t)m * K + k0 + kk];
        }
        __syncthreads();
        #pragma unroll
        for (int kk = 0; kk < 16; ++kk) {
            float4 av = *(const float4*)&As[kk][ty * 4];
            float4 bv = *(const float4*)&Ws[kk][tx * 4];
            float a[4] = {av.x, av.y, av.z, av.w};
            float b[4] = {bv.x, bv.y, bv.z, bv.w};
            #pragma unroll
            for (int i = 0; i < 4; ++i)
                #pragma unroll
                for (int j = 0; j < 4; ++j)
                    acc[i][j] += a[i] * b[j];
        }
    }
    int row0 = by * 64 + ty * 4;
    int col0 = bx * 64 + tx * 4;
    float4 bv = *(const float4*)&bias[col0];
    float bias4[4] = {bv.x, bv.y, bv.z, bv.w};
    #pragma unroll
    for (int i = 0; i < 4; ++i) {
        float vals[4];
        #pragma unroll
        for (int j = 0; j < 4; ++j) {
            float v = acc[i][j] + bias4[j];
            if (MODE == 2) v = 0.5f * v * (1.f + erff(v * 0.70710678118f));
            vals[j] = v;
        }
        float4 o;
        o.x = vals[0]; o.y = vals[1]; o.z = vals[2]; o.w = vals[3];
        if (MODE == 1) {
            float4 r = *(const float4*)&res[(size_t)(row0 + i) * N + col0];
            o.x += r.x; o.y += r.y; o.z += r.z; o.w += r.w;
        }
        *(float4*)&out[(size_t)(row0 + i) * N + col0] = o;
    }
}

// ---------------- flash attention (fp32, block-causal by frame) ----------------
// 1 thread = 1 query row; 128 threads/block = 128 rows; K/V tiles of 32 keys in LDS.
__global__ __launch_bounds__(128) void attn_kernel(
    const float* __restrict__ qkv, float* __restrict__ o)
{
    int qb = blockIdx.x & 15;          // 16 q-blocks of 128 rows
    int h  = (blockIdx.x >> 4) & 7;
    int b  = blockIdx.x >> 7;
    int tid = threadIdx.x;
    int q_s = qb * 128 + tid;
    const float4* qrow = (const float4*)(qkv + ((size_t)(b * SEQ + q_s)) * 1536 + h * 64);
    float4 q[16];
    #pragma unroll
    for (int i = 0; i < 16; ++i) q[i] = qrow[i];
    float m = -1e30f, l = 0.f;
    float4 oa[16] = {};
    int kend = ((q_s >> 5) + 1) << 5;      // keys with frame <= my frame
    __shared__ __align__(16) float4 Ks[32 * 16];
    __shared__ __align__(16) float4 Vs[32 * 16];
    int kmax = (qb + 1) * 128;             // block-level bound
    for (int kt = 0; kt < kmax; kt += 32) {
        __syncthreads();
        #pragma unroll
        for (int p = 0; p < 4; ++p) {
            int idx = p * 128 + tid;
            int key = idx >> 4, d4 = idx & 15;
            const float4* kr = (const float4*)(qkv + ((size_t)(b * SEQ + kt + key)) * 1536 + E + h * 64);
            Ks[idx] = kr[d4];
            Vs[idx] = kr[d4 + 128];        // V section is +E floats = +128 float4
        }
        __syncthreads();
        int jn = kend - kt; if (jn > 32) jn = 32;
        for (int j = 0; j < jn; ++j) {
            float s = 0.f;
            #pragma unroll
            for (int i = 0; i < 16; ++i) {
                float4 kv = Ks[j * 16 + i];
                s += q[i].x * kv.x + q[i].y * kv.y + q[i].z * kv.z + q[i].w * kv.w;
            }
            s *= 0.125f;                   // 1/sqrt(64)
            if (s > m) {
                float c = __expf(m - s);
                l *= c;
                #pragma unroll
                for (int i = 0; i < 16; ++i) {
                    oa[i].x *= c; oa[i].y *= c; oa[i].z *= c; oa[i].w *= c;
                }
                m = s;
            }
            float p = __expf(s - m);
            l += p;
            #pragma unroll
            for (int i = 0; i < 16; ++i) {
                float4 vv = Vs[j * 16 + i];
                oa[i].x += p * vv.x; oa[i].y += p * vv.y;
                oa[i].z += p * vv.z; oa[i].w += p * vv.w;
            }
        }
    }
    float inv = 1.f / l;
    float4* orow = (float4*)(o + ((size_t)(b * SEQ + q_s)) * E + h * 64);
    #pragma unroll
    for (int i = 0; i < 16; ++i) {
        float4 t = oa[i];
        t.x *= inv; t.y *= inv; t.z *= inv; t.w *= inv;
        orow[i] = t;
    }
}

extern "C" void kernel_launch(void* const* d_in, const int* in_sizes, int n_in,
                              void* d_out, int out_size, void* d_ws, size_t ws_size,
                              hipStream_t stream) {
    const int*   idx = (const int*)d_in[0];
    // d_in[1] = attention_mask (bool) — unused: mask is frame(key) <= frame(query), computed analytically
    const float* ce  = (const float*)d_in[2];
    const float* se  = (const float*)d_in[3];
    const float* tp  = (const float*)d_in[4];
    const float* jp  = (const float*)d_in[5];
    const float* ipw = (const float*)d_in[6];
    const float* ipb = (const float*)d_in[7];
    const float* ow  = (const float*)d_in[8];
    const float* ob  = (const float*)d_in[9];
    const float* l1g = (const float*)d_in[10];
    const float* l1b = (const float*)d_in[11];
    const float* w1  = (const float*)d_in[12];
    const float* b1  = (const float*)d_in[13];
    const float* w2  = (const float*)d_in[14];
    const float* b2  = (const float*)d_in[15];
    const float* l2g = (const float*)d_in[16];
    const float* l2b = (const float*)d_in[17];

    float* x    = (float*)d_out;                       // residual stream lives in d_out
    float* y    = (float*)d_ws;                        // [4096, 512]   8 MB
    // qkv (24 MB) and hbuf (32 MB) are never live at the same time -> union region (32 MB).
    float* qkv  = y + (size_t)M_TOK * E;               // [4096, 1536]
    float* hbuf = qkv;                                 // [4096, 2048] overlays qkv
    // total d_ws footprint: 8 MB + 32 MB = 40 MB

    embed_kernel<<<2048, 256, 0, stream>>>(idx, ce, se, tp, jp, x);

    for (int l = 0; l < NLAYER; ++l) {
        ln_kernel<<<1024, 256, 0, stream>>>(x, y, l1g + l * E, l1b + l * E);
        gemm_kernel<0><<<64 * 24, 256, 0, stream>>>(
            y, ipw + (size_t)l * 3 * E * E, ipb + (size_t)l * 3 * E, nullptr, qkv, 3 * E, E);
        attn_kernel<<<256, 128, 0, stream>>>(qkv, y);
        gemm_kernel<1><<<64 * 8, 256, 0, stream>>>(
            y, ow + (size_t)l * E * E, ob + (size_t)l * E, x, x, E, E);
        ln_kernel<<<1024, 256, 0, stream>>>(x, y, l2g + l * E, l2b + l * E);
        gemm_kernel<2><<<64 * 32, 256, 0, stream>>>(
            y, w1 + (size_t)l * DFF * E, b1 + (size_t)l * DFF, nullptr, hbuf, DFF, E);
        gemm_kernel<1><<<64 * 8, 256, 0, stream>>>(
            hbuf, w2 + (size_t)l * E * DFF, b2 + (size_t)l * E, x, x, E, DFF);
    }
}

// Round 3
// 3058.862 us; speedup vs baseline: 3.6102x; 3.6102x over previous
//
#include <hip/hip_runtime.h>
#include <hip/hip_bf16.h>
#include <math.h>

#define E 512
#define H_HEADS 8
#define DH 64
#define NLAYER 6
#define DFF 2048
#define SEQ 2048      // T*V
#define NB 2          // batch
#define M_TOK (NB*SEQ) // 4096 rows

typedef float f32x4_t __attribute__((ext_vector_type(4)));
typedef __bf16 bf16x8_t __attribute__((ext_vector_type(8)));
typedef short s16x8_t __attribute__((ext_vector_type(8)));

// float -> bf16 bits, round-to-nearest-even
__device__ __forceinline__ short f2bf(float f) {
    union { float f; unsigned u; } v; v.f = f;
    unsigned r = v.u + 0x7FFFu + ((v.u >> 16) & 1u);
    return (short)(r >> 16);
}

__device__ __forceinline__ bf16x8_t mk_frag(short4 lo, short4 hi) {
    s16x8_t t;
    t[0] = lo.x; t[1] = lo.y; t[2] = lo.z; t[3] = lo.w;
    t[4] = hi.x; t[5] = hi.y; t[6] = hi.z; t[7] = hi.w;
    return __builtin_bit_cast(bf16x8_t, t);
}

// ---------------- embedding: x = code_emb[idx] + stage + time_pos + joint_pos ----------------
__global__ __launch_bounds__(256) void embed_kernel(
    const int* __restrict__ idx, const float* __restrict__ ce,
    const float* __restrict__ se, const float* __restrict__ tp,
    const float* __restrict__ jp, float* __restrict__ x)
{
    int i = blockIdx.x * 256 + threadIdx.x;   // float4 index, total 524288
    int e4 = i & 127;                          // E/4 = 128
    int row = i >> 7;                          // 0..4095  = b*2048 + t*32 + v
    int v = row & 31;
    int t = (row >> 5) & 63;
    int code = idx[row];
    const float4* ce4 = (const float4*)ce;
    const float4* se4 = (const float4*)se;
    const float4* tp4 = (const float4*)tp;
    const float4* jp4 = (const float4*)jp;
    float4 a = ce4[code * 128 + e4];
    float4 b = se4[e4];
    float4 c = tp4[t * 128 + e4];
    float4 d = jp4[v * 128 + e4];
    float4 o;
    o.x = a.x + b.x + c.x + d.x;
    o.y = a.y + b.y + c.y + d.y;
    o.z = a.z + b.z + c.z + d.z;
    o.w = a.w + b.w + c.w + d.w;
    ((float4*)x)[i] = o;
}

// ---------------- LayerNorm: one wave per row of 512 ----------------
__global__ __launch_bounds__(256) void ln_kernel(
    const float* __restrict__ x, float* __restrict__ y,
    const float* __restrict__ g, const float* __restrict__ b)
{
    int wave = threadIdx.x >> 6;
    int lane = threadIdx.x & 63;
    int row = blockIdx.x * 4 + wave;
    const float4* xr = (const float4*)(x + (size_t)row * E);
    float4 v0 = xr[lane];
    float4 v1 = xr[lane + 64];
    float s  = v0.x + v0.y + v0.z + v0.w + v1.x + v1.y + v1.z + v1.w;
    float ss = v0.x*v0.x + v0.y*v0.y + v0.z*v0.z + v0.w*v0.w
             + v1.x*v1.x + v1.y*v1.y + v1.z*v1.z + v1.w*v1.w;
    #pragma unroll
    for (int off = 32; off; off >>= 1) {
        s  += __shfl_xor(s, off, 64);
        ss += __shfl_xor(ss, off, 64);
    }
    float mu = s * (1.f / E);
    float var = ss * (1.f / E) - mu * mu;
    float rs = rsqrtf(var + 1e-5f);
    const float4* g4 = (const float4*)g;
    const float4* b4 = (const float4*)b;
    float4* yr = (float4*)(y + (size_t)row * E);
    float4 gg = g4[lane], bb = b4[lane];
    float4 o;
    o.x = (v0.x - mu) * rs * gg.x + bb.x;
    o.y = (v0.y - mu) * rs * gg.y + bb.y;
    o.z = (v0.z - mu) * rs * gg.z + bb.z;
    o.w = (v0.w - mu) * rs * gg.w + bb.w;
    yr[lane] = o;
    gg = g4[lane + 64]; bb = b4[lane + 64];
    o.x = (v1.x - mu) * rs * gg.x + bb.x;
    o.y = (v1.y - mu) * rs * gg.y + bb.y;
    o.z = (v1.z - mu) * rs * gg.z + bb.z;
    o.w = (v1.w - mu) * rs * gg.w + bb.w;
    yr[lane + 64] = o;
}

// ---------------- GEMM: out[M,N] = A[M,K] @ W[N,K]^T + bias (+res / gelu) ----------------
// MODE 0: plain   MODE 1: + res (residual, res may alias out)   MODE 2: gelu(.)
template<int MODE>
__global__ __launch_bounds__(256) void gemm_kernel(
    const float* __restrict__ A, const float* __restrict__ W,
    const float* __restrict__ bias, const float* __restrict__ res,
    float* __restrict__ out, int N, int K)
{
    __shared__ __align__(16) float As[16][68];
    __shared__ __align__(16) float Ws[16][68];
    int nb = N >> 6;
    int bx = blockIdx.x % nb;
    int by = blockIdx.x / nb;
    int tid = threadIdx.x;
    int tx = tid & 15, ty = tid >> 4;
    float acc[4][4] = {};
    const float* Ab = A + (size_t)(by * 64) * K;
    const float* Wb = W + (size_t)(bx * 64) * K;
    for (int k0 = 0; k0 < K; k0 += 16) {
        __syncthreads();
        #pragma unroll
        for (int p = 0; p < 4; ++p) {
            int idx = p * 256 + tid;
            int kk = idx & 15, m = idx >> 4;
            As[kk][m] = Ab[(size_t)m * K + k0 + kk];
            Ws[kk][m] = Wb[(size_t)m * K + k0 + kk];
        }
        __syncthreads();
        #pragma unroll
        for (int kk = 0; kk < 16; ++kk) {
            float4 av = *(const float4*)&As[kk][ty * 4];
            float4 bv = *(const float4*)&Ws[kk][tx * 4];
            float a[4] = {av.x, av.y, av.z, av.w};
            float b[4] = {bv.x, bv.y, bv.z, bv.w};
            #pragma unroll
            for (int i = 0; i < 4; ++i)
                #pragma unroll
                for (int j = 0; j < 4; ++j)
                    acc[i][j] += a[i] * b[j];
        }
    }
    int row0 = by * 64 + ty * 4;
    int col0 = bx * 64 + tx * 4;
    float4 bv = *(const float4*)&bias[col0];
    float bias4[4] = {bv.x, bv.y, bv.z, bv.w};
    #pragma unroll
    for (int i = 0; i < 4; ++i) {
        float vals[4];
        #pragma unroll
        for (int j = 0; j < 4; ++j) {
            float v = acc[i][j] + bias4[j];
            if (MODE == 2) v = 0.5f * v * (1.f + erff(v * 0.70710678118f));
            vals[j] = v;
        }
        float4 o;
        o.x = vals[0]; o.y = vals[1]; o.z = vals[2]; o.w = vals[3];
        if (MODE == 1) {
            float4 r = *(const float4*)&res[(size_t)(row0 + i) * N + col0];
            o.x += r.x; o.y += r.y; o.z += r.z; o.w += r.w;
        }
        *(float4*)&out[(size_t)(row0 + i) * N + col0] = o;
    }
}

// ---------------- MFMA bf16 flash attention (block-causal by frame) ----------------
// Block = 4 waves x 16 q-rows = 64 q-rows. Grid = 32 qb x 8 h x 2 b = 512 blocks.
// Frame size (32) == KV tile size -> causal mask aligns to tiles, no masking needed.
// Swapped QK^T: S^T = mfma(K_frag, Q^T_frag) puts P^T directly in the B-fragment
// layout for the PV MFMA (O^T = mfma(V^T_frag, P^T_frag)). V staged transposed.
__global__ __launch_bounds__(256) void attn_mfma_kernel(
    const float* __restrict__ qkv, float* __restrict__ out)
{
    __shared__ __align__(16) short Qs[64 * 68];   // [q][dh] bf16, padded
    __shared__ __align__(16) short Ks[32 * 68];   // [key][dh] bf16, padded
    __shared__ __align__(16) short Vt[64 * 36];   // [dh][key] bf16, padded
    __shared__ __align__(16) float Ol[4 * 16 * 68]; // per-wave O bounce [q][dh]

    int qb = blockIdx.x & 31;
    int h  = (blockIdx.x >> 5) & 7;
    int b  = blockIdx.x >> 8;
    int tid  = threadIdx.x;
    int w    = tid >> 6;
    int lane = tid & 63;
    int g    = lane >> 4;
    int l16  = lane & 15;

    const float* base = qkv + (size_t)(b * SEQ) * 1536;

    // ---- stage Q block [64 q][64 dh] -> bf16 Qs ----
    #pragma unroll
    for (int u = 0; u < 4; ++u) {
        int f = tid + 256 * u;                 // 0..1023 float4-chunks
        int qr = f >> 4, c4 = f & 15;
        float4 v = *(const float4*)(base + (size_t)(qb * 64 + qr) * 1536 + h * 64 + c4 * 4);
        short4 s = { f2bf(v.x), f2bf(v.y), f2bf(v.z), f2bf(v.w) };
        *(short4*)&Qs[qr * 68 + c4 * 4] = s;
    }
    __syncthreads();

    // per-wave Q^T B-fragments: n = q = l16, k = dh = 4g + (j&3) + 16*(j>>2) + 32*ks
    bf16x8_t qf[2];
    #pragma unroll
    for (int ks = 0; ks < 2; ++ks) {
        const short* qrow = &Qs[(w * 16 + l16) * 68];
        short4 lo = *(const short4*)&qrow[4 * g + 32 * ks];
        short4 hi = *(const short4*)&qrow[4 * g + 16 + 32 * ks];
        qf[ks] = mk_frag(lo, hi);
    }

    f32x4_t oa[4] = {};                        // O^T accum: [dh-tile][reg], q = l16
    float mrun = -1e30f, lrun = 0.f;

    int kend = qb * 64 + (w >> 1) * 32 + 32;   // per-wave causal bound (multiple of 32)
    int kmax = (qb + 1) * 64;                  // block-level bound

    for (int kt = 0; kt < kmax; kt += 32) {
        __syncthreads();
        // ---- stage K [32][64] and V^T [64][32] ----
        #pragma unroll
        for (int u = 0; u < 2; ++u) {
            int f = tid + 256 * u;             // 0..511
            int key = f >> 4, c4 = f & 15;
            const float* row = base + (size_t)(kt + key) * 1536 + h * 64;
            float4 kv = *(const float4*)(row + 512 + c4 * 4);
            short4 s = { f2bf(kv.x), f2bf(kv.y), f2bf(kv.z), f2bf(kv.w) };
            *(short4*)&Ks[key * 68 + c4 * 4] = s;
            float4 vv = *(const float4*)(row + 1024 + c4 * 4);
            Vt[(c4 * 4 + 0) * 36 + key] = f2bf(vv.x);
            Vt[(c4 * 4 + 1) * 36 + key] = f2bf(vv.y);
            Vt[(c4 * 4 + 2) * 36 + key] = f2bf(vv.z);
            Vt[(c4 * 4 + 3) * 36 + key] = f2bf(vv.w);
        }
        __syncthreads();
        if (kt >= kend) continue;              // this wave done (barriers stay uniform)

        // ---- S^T[key][q] = K @ Q^T : 2 key-tiles x 2 dh-steps ----
        f32x4_t st[2];
        #pragma unroll
        for (int mt = 0; mt < 2; ++mt) {
            f32x4_t acc = {0.f, 0.f, 0.f, 0.f};
            #pragma unroll
            for (int ks = 0; ks < 2; ++ks) {
                const short* krow = &Ks[(mt * 16 + l16) * 68];
                short4 lo = *(const short4*)&krow[4 * g + 32 * ks];
                short4 hi = *(const short4*)&krow[4 * g + 16 + 32 * ks];
                acc = __builtin_amdgcn_mfma_f32_16x16x32_bf16(mk_frag(lo, hi), qf[ks], acc, 0, 0, 0);
            }
            st[mt] = acc;
        }

        // ---- online softmax: lane owns q = l16; keys 16*mt + 4g + reg ----
        float s8[8];
        #pragma unroll
        for (int mt = 0; mt < 2; ++mt)
            #pragma unroll
            for (int r = 0; r < 4; ++r)
                s8[mt * 4 + r] = st[mt][r] * 0.125f;
        float tm = s8[0];
        #pragma unroll
        for (int j = 1; j < 8; ++j) tm = fmaxf(tm, s8[j]);
        tm = fmaxf(tm, __shfl_xor(tm, 16));
        tm = fmaxf(tm, __shfl_xor(tm, 32));
        float mnew = fmaxf(mrun, tm);
        float c = __expf(mrun - mnew);
        mrun = mnew;
        float ps = 0.f;
        short pb[8];
        #pragma unroll
        for (int j = 0; j < 8; ++j) {
            float p = __expf(s8[j] - mrun);
            ps += p;
            pb[j] = f2bf(p);
        }
        ps += __shfl_xor(ps, 16);
        ps += __shfl_xor(ps, 32);
        lrun = lrun * c + ps;
        #pragma unroll
        for (int dt = 0; dt < 4; ++dt)
            #pragma unroll
            for (int r = 0; r < 4; ++r)
                oa[dt][r] *= c;
        s16x8_t pt;
        #pragma unroll
        for (int j = 0; j < 8; ++j) pt[j] = pb[j];
        bf16x8_t pf = __builtin_bit_cast(bf16x8_t, pt);

        // ---- O^T += V^T @ P^T : 4 dh-tiles, K-dim = 32 keys ----
        #pragma unroll
        for (int dt = 0; dt < 4; ++dt) {
            const short* vrow = &Vt[(dt * 16 + l16) * 36];
            short4 lo = *(const short4*)&vrow[4 * g];
            short4 hi = *(const short4*)&vrow[16 + 4 * g];
            oa[dt] = __builtin_amdgcn_mfma_f32_16x16x32_bf16(mk_frag(lo, hi), pf, oa[dt], 0, 0, 0);
        }
    }

    // ---- epilogue: O^T -> O via per-wave LDS bounce, coalesced global write ----
    float inv = 1.f / lrun;
    #pragma unroll
    for (int dt = 0; dt < 4; ++dt)
        #pragma unroll
        for (int r = 0; r < 4; ++r)
            Ol[(w * 16 + l16) * 68 + 16 * dt + 4 * g + r] = oa[dt][r] * inv;
    // same-wave readback (compiler inserts lgkmcnt wait; no cross-wave data)
    int qr = lane >> 2, cc = lane & 3;
    size_t gbase = (size_t)(b * SEQ + qb * 64 + w * 16 + qr) * E + h * 64;
    #pragma unroll
    for (int i = 0; i < 4; ++i) {
        float4 v = *(const float4*)&Ol[(w * 16 + qr) * 68 + (cc + 4 * i) * 4];
        *(float4*)&out[gbase + (cc + 4 * i) * 4] = v;
    }
}

extern "C" void kernel_launch(void* const* d_in, const int* in_sizes, int n_in,
                              void* d_out, int out_size, void* d_ws, size_t ws_size,
                              hipStream_t stream) {
    const int*   idx = (const int*)d_in[0];
    // d_in[1] = attention_mask (bool) — unused: mask is frame(key) <= frame(query), computed analytically
    const float* ce  = (const float*)d_in[2];
    const float* se  = (const float*)d_in[3];
    const float* tp  = (const float*)d_in[4];
    const float* jp  = (const float*)d_in[5];
    const float* ipw = (const float*)d_in[6];
    const float* ipb = (const float*)d_in[7];
    const float* ow  = (const float*)d_in[8];
    const float* ob  = (const float*)d_in[9];
    const float* l1g = (const float*)d_in[10];
    const float* l1b = (const float*)d_in[11];
    const float* w1  = (const float*)d_in[12];
    const float* b1  = (const float*)d_in[13];
    const float* w2  = (const float*)d_in[14];
    const float* b2  = (const float*)d_in[15];
    const float* l2g = (const float*)d_in[16];
    const float* l2b = (const float*)d_in[17];

    float* x    = (float*)d_out;                       // residual stream lives in d_out
    float* y    = (float*)d_ws;                        // [4096, 512]   8 MB
    // qkv (24 MB) and hbuf (32 MB) are never live at the same time -> union region (32 MB).
    float* qkv  = y + (size_t)M_TOK * E;               // [4096, 1536]
    float* hbuf = qkv;                                 // [4096, 2048] overlays qkv
    // total d_ws footprint: 8 MB + 32 MB = 40 MB

    embed_kernel<<<2048, 256, 0, stream>>>(idx, ce, se, tp, jp, x);

    for (int l = 0; l < NLAYER; ++l) {
        ln_kernel<<<1024, 256, 0, stream>>>(x, y, l1g + l * E, l1b + l * E);
        gemm_kernel<0><<<64 * 24, 256, 0, stream>>>(
            y, ipw + (size_t)l * 3 * E * E, ipb + (size_t)l * 3 * E, nullptr, qkv, 3 * E, E);
        attn_mfma_kernel<<<512, 256, 0, stream>>>(qkv, y);
        gemm_kernel<1><<<64 * 8, 256, 0, stream>>>(
            y, ow + (size_t)l * E * E, ob + (size_t)l * E, x, x, E, E);
        ln_kernel<<<1024, 256, 0, stream>>>(x, y, l2g + l * E, l2b + l * E);
        gemm_kernel<2><<<64 * 32, 256, 0, stream>>>(
            y, w1 + (size_t)l * DFF * E, b1 + (size_t)l * DFF, nullptr, hbuf, DFF, E);
        gemm_kernel<1><<<64 * 8, 256, 0, stream>>>(
            hbuf, w2 + (size_t)l * E * DFF, b2 + (size_t)l * E, x, x, E, DFF);
    }
}

// Round 5
// 1233.803 us; speedup vs baseline: 8.9504x; 2.4792x over previous
//
#include <hip/hip_runtime.h>
#include <hip/hip_bf16.h>
#include <math.h>

#define E 512
#define H_HEADS 8
#define DH 64
#define NLAYER 6
#define DFF 2048
#define SEQ 2048      // T*V
#define NB 2          // batch
#define M_TOK (NB*SEQ) // 4096 rows

typedef float f32x4_t __attribute__((ext_vector_type(4)));
typedef __bf16 bf16x8_t __attribute__((ext_vector_type(8)));
typedef short s16x8_t __attribute__((ext_vector_type(8)));

// float -> bf16 bits, round-to-nearest-even
__device__ __forceinline__ short f2bf(float f) {
    union { float f; unsigned u; } v; v.f = f;
    unsigned r = v.u + 0x7FFFu + ((v.u >> 16) & 1u);
    return (short)(r >> 16);
}

__device__ __forceinline__ bf16x8_t mk_frag(short4 lo, short4 hi) {
    s16x8_t t;
    t[0] = lo.x; t[1] = lo.y; t[2] = lo.z; t[3] = lo.w;
    t[4] = hi.x; t[5] = hi.y; t[6] = hi.z; t[7] = hi.w;
    return __builtin_bit_cast(bf16x8_t, t);
}

__device__ __forceinline__ void gload16(const void* g, void* l) {
    __builtin_amdgcn_global_load_lds(
        (const __attribute__((address_space(1))) void*)g,
        (__attribute__((address_space(3))) void*)l, 16, 0, 0);
}

// ---------------- embedding: x = code_emb[idx] + stage + time_pos + joint_pos ----------------
__global__ __launch_bounds__(256) void embed_kernel(
    const int* __restrict__ idx, const float* __restrict__ ce,
    const float* __restrict__ se, const float* __restrict__ tp,
    const float* __restrict__ jp, float* __restrict__ x)
{
    int i = blockIdx.x * 256 + threadIdx.x;   // float4 index, total 524288
    int e4 = i & 127;                          // E/4 = 128
    int row = i >> 7;                          // 0..4095  = b*2048 + t*32 + v
    int v = row & 31;
    int t = (row >> 5) & 63;
    int code = idx[row];
    const float4* ce4 = (const float4*)ce;
    const float4* se4 = (const float4*)se;
    const float4* tp4 = (const float4*)tp;
    const float4* jp4 = (const float4*)jp;
    float4 a = ce4[code * 128 + e4];
    float4 b = se4[e4];
    float4 c = tp4[t * 128 + e4];
    float4 d = jp4[v * 128 + e4];
    float4 o;
    o.x = a.x + b.x + c.x + d.x;
    o.y = a.y + b.y + c.y + d.y;
    o.z = a.z + b.z + c.z + d.z;
    o.w = a.w + b.w + c.w + d.w;
    ((float4*)x)[i] = o;
}

// ---------------- weight cast: one layer's 4 weight mats fp32 -> bf16 ----------------
// segments (in 8-elem chunks): ipw 98304 | ow 32768 | w1 131072 | w2 131072  (sum 393216)
__global__ __launch_bounds__(256) void cast4_kernel(
    const float* __restrict__ w0, const float* __restrict__ w1,
    const float* __restrict__ w2, const float* __restrict__ w3,
    short* __restrict__ o)
{
    int i = blockIdx.x * 256 + threadIdx.x;   // chunk of 8
    const float* src; int off;
    if (i < 98304)       { src = w0; off = i; }
    else if (i < 131072) { src = w1; off = i - 98304; }
    else if (i < 262144) { src = w2; off = i - 131072; }
    else                 { src = w3; off = i - 262144; }
    float4 a = ((const float4*)src)[off * 2];
    float4 b = ((const float4*)src)[off * 2 + 1];
    s16x8_t s;
    s[0] = f2bf(a.x); s[1] = f2bf(a.y); s[2] = f2bf(a.z); s[3] = f2bf(a.w);
    s[4] = f2bf(b.x); s[5] = f2bf(b.y); s[6] = f2bf(b.z); s[7] = f2bf(b.w);
    *(s16x8_t*)&o[(size_t)i * 8] = s;
}

// ---------------- LayerNorm: one wave per row of 512, bf16 output ----------------
__global__ __launch_bounds__(256) void ln_kernel(
    const float* __restrict__ x, short* __restrict__ y,
    const float* __restrict__ g, const float* __restrict__ b)
{
    int wave = threadIdx.x >> 6;
    int lane = threadIdx.x & 63;
    int row = blockIdx.x * 4 + wave;
    const float4* xr = (const float4*)(x + (size_t)row * E);
    float4 v0 = xr[lane];
    float4 v1 = xr[lane + 64];
    float s  = v0.x + v0.y + v0.z + v0.w + v1.x + v1.y + v1.z + v1.w;
    float ss = v0.x*v0.x + v0.y*v0.y + v0.z*v0.z + v0.w*v0.w
             + v1.x*v1.x + v1.y*v1.y + v1.z*v1.z + v1.w*v1.w;
    #pragma unroll
    for (int off = 32; off; off >>= 1) {
        s  += __shfl_xor(s, off, 64);
        ss += __shfl_xor(ss, off, 64);
    }
    float mu = s * (1.f / E);
    float var = ss * (1.f / E) - mu * mu;
    float rs = rsqrtf(var + 1e-5f);
    const float4* g4 = (const float4*)g;
    const float4* b4 = (const float4*)b;
    float4 gg = g4[lane], bb = b4[lane];
    short4 o;
    o.x = f2bf((v0.x - mu) * rs * gg.x + bb.x);
    o.y = f2bf((v0.y - mu) * rs * gg.y + bb.y);
    o.z = f2bf((v0.z - mu) * rs * gg.z + bb.z);
    o.w = f2bf((v0.w - mu) * rs * gg.w + bb.w);
    *(short4*)&y[(size_t)row * E + lane * 4] = o;
    gg = g4[lane + 64]; bb = b4[lane + 64];
    o.x = f2bf((v1.x - mu) * rs * gg.x + bb.x);
    o.y = f2bf((v1.y - mu) * rs * gg.y + bb.y);
    o.z = f2bf((v1.z - mu) * rs * gg.z + bb.z);
    o.w = f2bf((v1.w - mu) * rs * gg.w + bb.w);
    *(short4*)&y[(size_t)row * E + 256 + lane * 4] = o;
}

// ---------------- bf16 MFMA GEMM: out[M,N] = A[M,K] @ W[N,K]^T + bias ----------------
// 128x128 tile, 4 waves (2x2), wave = 64x64 = 4x4 fragments of 16x16, MFMA 16x16x32,
// BK=64, global_load_lds width-16 staging, 2-barrier K-loop (m97 structure).
// MODE 0: bias -> bf16 out    MODE 1: bias + res -> fp32 out    MODE 2: gelu(bias+.) -> bf16 out
template<int MODE>
__global__ __launch_bounds__(256) void gemm_mfma_kernel(
    const short* __restrict__ A, const short* __restrict__ W,
    const float* __restrict__ bias, const float* __restrict__ res,
    void* __restrict__ out, int N, int K)
{
    __shared__ short As[128 * 64];
    __shared__ short Bs[128 * 64];
    int nb = N >> 7;
    int bx = blockIdx.x % nb;
    int by = blockIdx.x / nb;
    int tid = threadIdx.x;
    int lane = tid & 63, g = lane >> 4, l16 = lane & 15;
    int w = tid >> 6, wm = w >> 1, wn = w & 1;
    int wbase = tid & 192;                     // (tid>>6)*64 chunk base

    f32x4_t acc[4][4] = {};
    const short* Ab = A + (size_t)(by * 128) * K;
    const short* Wb = W + (size_t)(bx * 128) * K;

    for (int k0 = 0; k0 < K; k0 += 64) {
        __syncthreads();
        #pragma unroll
        for (int u = 0; u < 4; ++u) {
            int c = u * 256 + tid;
            int row = c >> 3, c8 = c & 7;
            gload16(Ab + (size_t)row * K + k0 + c8 * 8, As + (u * 256 + wbase) * 8);
            gload16(Wb + (size_t)row * K + k0 + c8 * 8, Bs + (u * 256 + wbase) * 8);
        }
        __syncthreads();                       // drains vmcnt before any wave reads
        #pragma unroll
        for (int ks = 0; ks < 2; ++ks) {
            bf16x8_t af[4], bf[4];
            #pragma unroll
            for (int i = 0; i < 4; ++i) {
                af[i] = *(const bf16x8_t*)&As[(wm * 64 + i * 16 + l16) * 64 + ks * 32 + g * 8];
                bf[i] = *(const bf16x8_t*)&Bs[(wn * 64 + i * 16 + l16) * 64 + ks * 32 + g * 8];
            }
            #pragma unroll
            for (int mi = 0; mi < 4; ++mi)
                #pragma unroll
                for (int ni = 0; ni < 4; ++ni)
                    acc[mi][ni] = __builtin_amdgcn_mfma_f32_16x16x32_bf16(
                        af[mi], bf[ni], acc[mi][ni], 0, 0, 0);
        }
    }

    int gm0 = by * 128 + wm * 64;
    int gn0 = bx * 128 + wn * 64;
    #pragma unroll
    for (int ni = 0; ni < 4; ++ni) {
        int gn = gn0 + ni * 16 + l16;
        float bv = bias[gn];
        #pragma unroll
        for (int mi = 0; mi < 4; ++mi) {
            #pragma unroll
            for (int r = 0; r < 4; ++r) {
                int gm = gm0 + mi * 16 + g * 4 + r;
                float v = acc[mi][ni][r] + bv;
                if (MODE == 2) v = 0.5f * v * (1.f + erff(v * 0.70710678118f));
                if (MODE == 1) {
                    v += res[(size_t)gm * N + gn];
                    ((float*)out)[(size_t)gm * N + gn] = v;
                } else {
                    ((short*)out)[(size_t)gm * N + gn] = f2bf(v);
                }
            }
        }
    }
}

// ---------------- MFMA bf16 flash attention (block-causal by frame) ----------------
// qkv is bf16 [4096][1536]; output bf16 [4096][512]. Structure verified in round 2.
__global__ __launch_bounds__(256) void attn_mfma_kernel(
    const short* __restrict__ qkv, short* __restrict__ out)
{
    __shared__ __align__(16) short Qs[64 * 68];   // [q][dh] bf16, padded
    __shared__ __align__(16) short Ks[32 * 68];   // [key][dh] bf16, padded
    __shared__ __align__(16) short Vt[64 * 36];   // [dh][key] bf16, padded
    __shared__ __align__(16) float Ol[4 * 16 * 68]; // per-wave O bounce [q][dh]

    int qb = blockIdx.x & 31;
    int h  = (blockIdx.x >> 5) & 7;
    int b  = blockIdx.x >> 8;
    int tid  = threadIdx.x;
    int w    = tid >> 6;
    int lane = tid & 63;
    int g    = lane >> 4;
    int l16  = lane & 15;

    const short* base = qkv + (size_t)(b * SEQ) * 1536;

    // ---- stage Q block [64 q][64 dh] ----
    #pragma unroll
    for (int u = 0; u < 4; ++u) {
        int f = tid + 256 * u;                 // 0..1023 short4-chunks
        int qr = f >> 4, c4 = f & 15;
        short4 v = *(const short4*)(base + (size_t)(qb * 64 + qr) * 1536 + h * 64 + c4 * 4);
        *(short4*)&Qs[qr * 68 + c4 * 4] = v;
    }
    __syncthreads();

    // per-wave Q^T B-fragments: n = q = l16, k = dh = 4g + (j&3) + 16*(j>>2) + 32*ks
    bf16x8_t qf[2];
    #pragma unroll
    for (int ks = 0; ks < 2; ++ks) {
        const short* qrow = &Qs[(w * 16 + l16) * 68];
        short4 lo = *(const short4*)&qrow[4 * g + 32 * ks];
        short4 hi = *(const short4*)&qrow[4 * g + 16 + 32 * ks];
        qf[ks] = mk_frag(lo, hi);
    }

    f32x4_t oa[4] = {};                        // O^T accum: [dh-tile][reg], q = l16
    float mrun = -1e30f, lrun = 0.f;

    int kend = qb * 64 + (w >> 1) * 32 + 32;   // per-wave causal bound (multiple of 32)
    int kmax = (qb + 1) * 64;                  // block-level bound

    for (int kt = 0; kt < kmax; kt += 32) {
        __syncthreads();
        // ---- stage K [32][64] and V^T [64][32] ----
        #pragma unroll
        for (int u = 0; u < 2; ++u) {
            int f = tid + 256 * u;             // 0..511
            int key = f >> 4, c4 = f & 15;
            const short* row = base + (size_t)(kt + key) * 1536 + h * 64;
            short4 kv = *(const short4*)(row + 512 + c4 * 4);
            *(short4*)&Ks[key * 68 + c4 * 4] = kv;
            short4 vv = *(const short4*)(row + 1024 + c4 * 4);
            Vt[(c4 * 4 + 0) * 36 + key] = vv.x;
            Vt[(c4 * 4 + 1) * 36 + key] = vv.y;
            Vt[(c4 * 4 + 2) * 36 + key] = vv.z;
            Vt[(c4 * 4 + 3) * 36 + key] = vv.w;
        }
        __syncthreads();
        if (kt >= kend) continue;              // this wave done (barriers stay uniform)

        // ---- S^T[key][q] = K @ Q^T ----
        f32x4_t st[2];
        #pragma unroll
        for (int mt = 0; mt < 2; ++mt) {
            f32x4_t acc = {0.f, 0.f, 0.f, 0.f};
            #pragma unroll
            for (int ks = 0; ks < 2; ++ks) {
                const short* krow = &Ks[(mt * 16 + l16) * 68];
                short4 lo = *(const short4*)&krow[4 * g + 32 * ks];
                short4 hi = *(const short4*)&krow[4 * g + 16 + 32 * ks];
                acc = __builtin_amdgcn_mfma_f32_16x16x32_bf16(mk_frag(lo, hi), qf[ks], acc, 0, 0, 0);
            }
            st[mt] = acc;
        }

        // ---- online softmax: lane owns q = l16; keys 16*mt + 4g + reg ----
        float s8[8];
        #pragma unroll
        for (int mt = 0; mt < 2; ++mt)
            #pragma unroll
            for (int r = 0; r < 4; ++r)
                s8[mt * 4 + r] = st[mt][r] * 0.125f;
        float tm = s8[0];
        #pragma unroll
        for (int j = 1; j < 8; ++j) tm = fmaxf(tm, s8[j]);
        tm = fmaxf(tm, __shfl_xor(tm, 16));
        tm = fmaxf(tm, __shfl_xor(tm, 32));
        float mnew = fmaxf(mrun, tm);
        float c = __expf(mrun - mnew);
        mrun = mnew;
        float ps = 0.f;
        short pb[8];
        #pragma unroll
        for (int j = 0; j < 8; ++j) {
            float p = __expf(s8[j] - mrun);
            ps += p;
            pb[j] = f2bf(p);
        }
        ps += __shfl_xor(ps, 16);
        ps += __shfl_xor(ps, 32);
        lrun = lrun * c + ps;
        #pragma unroll
        for (int dt = 0; dt < 4; ++dt)
            #pragma unroll
            for (int r = 0; r < 4; ++r)
                oa[dt][r] *= c;
        s16x8_t pt;
        #pragma unroll
        for (int j = 0; j < 8; ++j) pt[j] = pb[j];
        bf16x8_t pf = __builtin_bit_cast(bf16x8_t, pt);

        // ---- O^T += V^T @ P^T : 4 dh-tiles, K-dim = 32 keys ----
        #pragma unroll
        for (int dt = 0; dt < 4; ++dt) {
            const short* vrow = &Vt[(dt * 16 + l16) * 36];
            short4 lo = *(const short4*)&vrow[4 * g];
            short4 hi = *(const short4*)&vrow[16 + 4 * g];
            oa[dt] = __builtin_amdgcn_mfma_f32_16x16x32_bf16(mk_frag(lo, hi), pf, oa[dt], 0, 0, 0);
        }
    }

    // ---- epilogue: O^T -> O via per-wave LDS bounce, coalesced bf16 write ----
    float inv = 1.f / lrun;
    #pragma unroll
    for (int dt = 0; dt < 4; ++dt)
        #pragma unroll
        for (int r = 0; r < 4; ++r)
            Ol[(w * 16 + l16) * 68 + 16 * dt + 4 * g + r] = oa[dt][r] * inv;
    int qr = lane >> 2, cc = lane & 3;
    const float* orow = &Ol[(w * 16 + qr) * 68 + cc * 16];
    s16x8_t s0, s1;
    #pragma unroll
    for (int j = 0; j < 8; ++j) { s0[j] = f2bf(orow[j]); s1[j] = f2bf(orow[8 + j]); }
    size_t gb = (size_t)(b * SEQ + qb * 64 + w * 16 + qr) * E + h * 64 + cc * 16;
    *(s16x8_t*)&out[gb] = s0;
    *(s16x8_t*)&out[gb + 8] = s1;
}

extern "C" void kernel_launch(void* const* d_in, const int* in_sizes, int n_in,
                              void* d_out, int out_size, void* d_ws, size_t ws_size,
                              hipStream_t stream) {
    const int*   idx = (const int*)d_in[0];
    // d_in[1] = attention_mask (bool) — unused: mask is frame(key) <= frame(query), computed analytically
    const float* ce  = (const float*)d_in[2];
    const float* se  = (const float*)d_in[3];
    const float* tp  = (const float*)d_in[4];
    const float* jp  = (const float*)d_in[5];
    const float* ipw = (const float*)d_in[6];
    const float* ipb = (const float*)d_in[7];
    const float* ow  = (const float*)d_in[8];
    const float* ob  = (const float*)d_in[9];
    const float* l1g = (const float*)d_in[10];
    const float* l1b = (const float*)d_in[11];
    const float* w1  = (const float*)d_in[12];
    const float* b1  = (const float*)d_in[13];
    const float* w2  = (const float*)d_in[14];
    const float* b2  = (const float*)d_in[15];
    const float* l2g = (const float*)d_in[16];
    const float* l2b = (const float*)d_in[17];

    float* x = (float*)d_out;                              // residual stream (fp32)
    // workspace layout (26.3 MB total):
    short* y_bf   = (short*)d_ws;                          // [4096][512]  bf16, 4 MB
    short* qkv_bf = (short*)((char*)d_ws + (4u << 20));    // [4096][1536] bf16 (12 MB)
    short* h_bf   = qkv_bf;                                // [4096][2048] bf16 overlays qkv (16 MB)
    short* wb     = (short*)((char*)d_ws + (20u << 20));   // per-layer bf16 weights, 6.3 MB
    short* wip = wb;                  // [1536][512]
    short* wob = wb + 786432;         // [512][512]
    short* w1b = wb + 1048576;        // [2048][512]
    short* w2b = wb + 2097152;        // [512][2048]

    embed_kernel<<<2048, 256, 0, stream>>>(idx, ce, se, tp, jp, x);

    for (int l = 0; l < NLAYER; ++l) {
        cast4_kernel<<<1536, 256, 0, stream>>>(
            ipw + (size_t)l * 786432, ow + (size_t)l * 262144,
            w1 + (size_t)l * 1048576, w2 + (size_t)l * 1048576, wb);
        ln_kernel<<<1024, 256, 0, stream>>>(x, y_bf, l1g + l * E, l1b + l * E);
        gemm_mfma_kernel<0><<<32 * 12, 256, 0, stream>>>(
            y_bf, wip, ipb + (size_t)l * 1536, nullptr, qkv_bf, 1536, 512);
        attn_mfma_kernel<<<512, 256, 0, stream>>>(qkv_bf, y_bf);
        gemm_mfma_kernel<1><<<32 * 4, 256, 0, stream>>>(
            y_bf, wob, ob + (size_t)l * E, x, x, 512, 512);
        ln_kernel<<<1024, 256, 0, stream>>>(x, y_bf, l2g + l * E, l2b + l * E);
        gemm_mfma_kernel<2><<<32 * 16, 256, 0, stream>>>(
            y_bf, w1b, b1 + (size_t)l * DFF, nullptr, h_bf, 2048, 512);
        gemm_mfma_kernel<1><<<32 * 4, 256, 0, stream>>>(
            h_bf, w2b, b2 + (size_t)l * E, x, x, 512, 2048);
    }
}

// Round 6
// 1230.661 us; speedup vs baseline: 8.9732x; 1.0026x over previous
//
#include <hip/hip_runtime.h>
#include <hip/hip_bf16.h>
#include <math.h>

#define E 512
#define H_HEADS 8
#define DH 64
#define NLAYER 6
#define DFF 2048
#define SEQ 2048      // T*V
#define NB 2          // batch
#define M_TOK (NB*SEQ) // 4096 rows

typedef float f32x4_t __attribute__((ext_vector_type(4)));
typedef __bf16 bf16x8_t __attribute__((ext_vector_type(8)));
typedef short s16x8_t __attribute__((ext_vector_type(8)));

// float -> bf16 bits, round-to-nearest-even
__device__ __forceinline__ short f2bf(float f) {
    union { float f; unsigned u; } v; v.f = f;
    unsigned r = v.u + 0x7FFFu + ((v.u >> 16) & 1u);
    return (short)(r >> 16);
}

__device__ __forceinline__ bf16x8_t mk_frag(short4 lo, short4 hi) {
    s16x8_t t;
    t[0] = lo.x; t[1] = lo.y; t[2] = lo.z; t[3] = lo.w;
    t[4] = hi.x; t[5] = hi.y; t[6] = hi.z; t[7] = hi.w;
    return __builtin_bit_cast(bf16x8_t, t);
}

__device__ __forceinline__ void gload16(const void* g, void* l) {
    __builtin_amdgcn_global_load_lds(
        (const __attribute__((address_space(1))) void*)g,
        (__attribute__((address_space(3))) void*)l, 16, 0, 0);
}

// ---------------- embedding: x = code_emb[idx] + stage + time_pos + joint_pos ----------------
__global__ __launch_bounds__(256) void embed_kernel(
    const int* __restrict__ idx, const float* __restrict__ ce,
    const float* __restrict__ se, const float* __restrict__ tp,
    const float* __restrict__ jp, float* __restrict__ x)
{
    int i = blockIdx.x * 256 + threadIdx.x;   // float4 index, total 524288
    int e4 = i & 127;                          // E/4 = 128
    int row = i >> 7;                          // 0..4095  = b*2048 + t*32 + v
    int v = row & 31;
    int t = (row >> 5) & 63;
    int code = idx[row];
    const float4* ce4 = (const float4*)ce;
    const float4* se4 = (const float4*)se;
    const float4* tp4 = (const float4*)tp;
    const float4* jp4 = (const float4*)jp;
    float4 a = ce4[code * 128 + e4];
    float4 b = se4[e4];
    float4 c = tp4[t * 128 + e4];
    float4 d = jp4[v * 128 + e4];
    float4 o;
    o.x = a.x + b.x + c.x + d.x;
    o.y = a.y + b.y + c.y + d.y;
    o.z = a.z + b.z + c.z + d.z;
    o.w = a.w + b.w + c.w + d.w;
    ((float4*)x)[i] = o;
}

// ---------------- weight cast: one layer's 4 weight mats fp32 -> bf16 ----------------
// segments (in 8-elem chunks): ipw 98304 | ow 32768 | w1 131072 | w2 131072  (sum 393216)
__global__ __launch_bounds__(256) void cast4_kernel(
    const float* __restrict__ w0, const float* __restrict__ w1,
    const float* __restrict__ w2, const float* __restrict__ w3,
    short* __restrict__ o)
{
    int i = blockIdx.x * 256 + threadIdx.x;   // chunk of 8
    const float* src; int off;
    if (i < 98304)       { src = w0; off = i; }
    else if (i < 131072) { src = w1; off = i - 98304; }
    else if (i < 262144) { src = w2; off = i - 131072; }
    else                 { src = w3; off = i - 262144; }
    float4 a = ((const float4*)src)[off * 2];
    float4 b = ((const float4*)src)[off * 2 + 1];
    s16x8_t s;
    s[0] = f2bf(a.x); s[1] = f2bf(a.y); s[2] = f2bf(a.z); s[3] = f2bf(a.w);
    s[4] = f2bf(b.x); s[5] = f2bf(b.y); s[6] = f2bf(b.z); s[7] = f2bf(b.w);
    *(s16x8_t*)&o[(size_t)i * 8] = s;
}

// ---------------- LayerNorm: one wave per row of 512, bf16 output ----------------
__global__ __launch_bounds__(256) void ln_kernel(
    const float* __restrict__ x, short* __restrict__ y,
    const float* __restrict__ g, const float* __restrict__ b)
{
    int wave = threadIdx.x >> 6;
    int lane = threadIdx.x & 63;
    int row = blockIdx.x * 4 + wave;
    const float4* xr = (const float4*)(x + (size_t)row * E);
    float4 v0 = xr[lane];
    float4 v1 = xr[lane + 64];
    float s  = v0.x + v0.y + v0.z + v0.w + v1.x + v1.y + v1.z + v1.w;
    float ss = v0.x*v0.x + v0.y*v0.y + v0.z*v0.z + v0.w*v0.w
             + v1.x*v1.x + v1.y*v1.y + v1.z*v1.z + v1.w*v1.w;
    #pragma unroll
    for (int off = 32; off; off >>= 1) {
        s  += __shfl_xor(s, off, 64);
        ss += __shfl_xor(ss, off, 64);
    }
    float mu = s * (1.f / E);
    float var = ss * (1.f / E) - mu * mu;
    float rs = rsqrtf(var + 1e-5f);
    const float4* g4 = (const float4*)g;
    const float4* b4 = (const float4*)b;
    float4 gg = g4[lane], bb = b4[lane];
    short4 o;
    o.x = f2bf((v0.x - mu) * rs * gg.x + bb.x);
    o.y = f2bf((v0.y - mu) * rs * gg.y + bb.y);
    o.z = f2bf((v0.z - mu) * rs * gg.z + bb.z);
    o.w = f2bf((v0.w - mu) * rs * gg.w + bb.w);
    *(short4*)&y[(size_t)row * E + lane * 4] = o;
    gg = g4[lane + 64]; bb = b4[lane + 64];
    o.x = f2bf((v1.x - mu) * rs * gg.x + bb.x);
    o.y = f2bf((v1.y - mu) * rs * gg.y + bb.y);
    o.z = f2bf((v1.z - mu) * rs * gg.z + bb.z);
    o.w = f2bf((v1.w - mu) * rs * gg.w + bb.w);
    *(short4*)&y[(size_t)row * E + 256 + lane * 4] = o;
}

// ---------------- bf16 MFMA GEMM: out[M,N] = A[M,K] @ W[N,K]^T + bias ----------------
// 128x128 tile, 4 waves (2x2), wave = 64x64 = 4x4 fragments of 16x16, MFMA 16x16x32,
// BK=64, global_load_lds width-16 staging, 2-barrier K-loop (m97 structure).
// MODE 0: bias -> bf16 out    MODE 1: bias + res -> fp32 out    MODE 2: gelu(bias+.) -> bf16 out
template<int MODE>
__global__ __launch_bounds__(256) void gemm_mfma_kernel(
    const short* __restrict__ A, const short* __restrict__ W,
    const float* __restrict__ bias, const float* __restrict__ res,
    void* __restrict__ out, int N, int K)
{
    __shared__ short As[128 * 64];
    __shared__ short Bs[128 * 64];
    int nb = N >> 7;
    int bx = blockIdx.x % nb;
    int by = blockIdx.x / nb;
    int tid = threadIdx.x;
    int lane = tid & 63, g = lane >> 4, l16 = lane & 15;
    int w = tid >> 6, wm = w >> 1, wn = w & 1;
    int wbase = tid & 192;                     // (tid>>6)*64 chunk base

    f32x4_t acc[4][4] = {};
    const short* Ab = A + (size_t)(by * 128) * K;
    const short* Wb = W + (size_t)(bx * 128) * K;

    for (int k0 = 0; k0 < K; k0 += 64) {
        __syncthreads();
        #pragma unroll
        for (int u = 0; u < 4; ++u) {
            int c = u * 256 + tid;
            int row = c >> 3, c8 = c & 7;
            gload16(Ab + (size_t)row * K + k0 + c8 * 8, As + (u * 256 + wbase) * 8);
            gload16(Wb + (size_t)row * K + k0 + c8 * 8, Bs + (u * 256 + wbase) * 8);
        }
        __syncthreads();                       // drains vmcnt before any wave reads
        #pragma unroll
        for (int ks = 0; ks < 2; ++ks) {
            bf16x8_t af[4], bf[4];
            #pragma unroll
            for (int i = 0; i < 4; ++i) {
                af[i] = *(const bf16x8_t*)&As[(wm * 64 + i * 16 + l16) * 64 + ks * 32 + g * 8];
                bf[i] = *(const bf16x8_t*)&Bs[(wn * 64 + i * 16 + l16) * 64 + ks * 32 + g * 8];
            }
            #pragma unroll
            for (int mi = 0; mi < 4; ++mi)
                #pragma unroll
                for (int ni = 0; ni < 4; ++ni)
                    acc[mi][ni] = __builtin_amdgcn_mfma_f32_16x16x32_bf16(
                        af[mi], bf[ni], acc[mi][ni], 0, 0, 0);
        }
    }

    int gm0 = by * 128 + wm * 64;
    int gn0 = bx * 128 + wn * 64;
    #pragma unroll
    for (int ni = 0; ni < 4; ++ni) {
        int gn = gn0 + ni * 16 + l16;
        float bv = bias[gn];
        #pragma unroll
        for (int mi = 0; mi < 4; ++mi) {
            #pragma unroll
            for (int r = 0; r < 4; ++r) {
                int gm = gm0 + mi * 16 + g * 4 + r;
                float v = acc[mi][ni][r] + bv;
                if (MODE == 2) v = 0.5f * v * (1.f + erff(v * 0.70710678118f));
                if (MODE == 1) {
                    v += res[(size_t)gm * N + gn];
                    ((float*)out)[(size_t)gm * N + gn] = v;
                } else {
                    ((short*)out)[(size_t)gm * N + gn] = f2bf(v);
                }
            }
        }
    }
}

// ---------------- MFMA bf16 flash attention (block-causal by frame) ----------------
// 32 q-rows per block (one frame), 2 waves x 16 rows. Grid = 64 qb x 8 h x 2 b = 1024,
// longest-first (qb descending). kend = (qb+1)*32 uniform across the block.
// Register-prefetch double-buffer: next tile's K/V loaded to regs during compute.
// Fragment maps identical to the round-2/3 verified kernel.
__global__ __launch_bounds__(128) void attn_mfma_kernel(
    const short* __restrict__ qkv, short* __restrict__ out)
{
    __shared__ __align__(16) short Qs[32 * 68];   // [q][dh] bf16, padded
    __shared__ __align__(16) short Ks[32 * 68];   // [key][dh] bf16, padded
    __shared__ __align__(16) short Vt[64 * 36];   // [dh][key] bf16, padded
    __shared__ __align__(16) float Ol[2 * 16 * 68]; // per-wave O bounce [q][dh]

    int bid = blockIdx.x;
    int qb = 63 - (bid & 63);                  // longest-first
    int h  = (bid >> 6) & 7;
    int b  = bid >> 9;
    int tid  = threadIdx.x;
    int w    = tid >> 6;
    int lane = tid & 63;
    int g    = lane >> 4;
    int l16  = lane & 15;

    const short* base = qkv + (size_t)(b * SEQ) * 1536;

    // ---- stage Q block [32 q][64 dh] ----
    #pragma unroll
    for (int u = 0; u < 4; ++u) {
        int f = tid + 128 * u;                 // 0..511 short4-chunks
        int qr = f >> 4, c4 = f & 15;
        short4 v = *(const short4*)(base + (size_t)(qb * 32 + qr) * 1536 + h * 64 + c4 * 4);
        *(short4*)&Qs[qr * 68 + c4 * 4] = v;
    }

    // ---- prefetch tile 0 K/V into registers ----
    int kend = (qb + 1) * 32;
    short4 kreg[4], vreg[4];
    #pragma unroll
    for (int u = 0; u < 4; ++u) {
        int f = tid + 128 * u;                 // 0..511
        int key = f >> 4, c4 = f & 15;
        const short* row = base + (size_t)key * 1536 + h * 64;
        kreg[u] = *(const short4*)(row + 512 + c4 * 4);
        vreg[u] = *(const short4*)(row + 1024 + c4 * 4);
    }
    __syncthreads();

    // per-wave Q^T B-fragments: n = q = l16, k = dh = 4g + (j&3) + 16*(j>>2) + 32*ks
    bf16x8_t qf[2];
    #pragma unroll
    for (int ks = 0; ks < 2; ++ks) {
        const short* qrow = &Qs[(w * 16 + l16) * 68];
        short4 lo = *(const short4*)&qrow[4 * g + 32 * ks];
        short4 hi = *(const short4*)&qrow[4 * g + 16 + 32 * ks];
        qf[ks] = mk_frag(lo, hi);
    }

    f32x4_t oa[4] = {};                        // O^T accum: [dh-tile][reg], q = l16
    float mrun = -1e30f, lrun = 0.f;

    for (int kt = 0; kt < kend; kt += 32) {
        __syncthreads();                       // prev tile's LDS reads complete
        // ---- write prefetched K/V regs -> LDS (K row-major, V transposed) ----
        #pragma unroll
        for (int u = 0; u < 4; ++u) {
            int f = tid + 128 * u;
            int key = f >> 4, c4 = f & 15;
            *(short4*)&Ks[key * 68 + c4 * 4] = kreg[u];
            Vt[(c4 * 4 + 0) * 36 + key] = vreg[u].x;
            Vt[(c4 * 4 + 1) * 36 + key] = vreg[u].y;
            Vt[(c4 * 4 + 2) * 36 + key] = vreg[u].z;
            Vt[(c4 * 4 + 3) * 36 + key] = vreg[u].w;
        }
        // ---- issue next tile's global loads (latency hides under compute) ----
        if (kt + 32 < kend) {
            #pragma unroll
            for (int u = 0; u < 4; ++u) {
                int f = tid + 128 * u;
                int key = f >> 4, c4 = f & 15;
                const short* row = base + (size_t)(kt + 32 + key) * 1536 + h * 64;
                kreg[u] = *(const short4*)(row + 512 + c4 * 4);
                vreg[u] = *(const short4*)(row + 1024 + c4 * 4);
            }
        }
        __syncthreads();                       // LDS writes visible

        // ---- S^T[key][q] = K @ Q^T ----
        f32x4_t st[2];
        __builtin_amdgcn_s_setprio(1);
        #pragma unroll
        for (int mt = 0; mt < 2; ++mt) {
            f32x4_t acc = {0.f, 0.f, 0.f, 0.f};
            #pragma unroll
            for (int ks = 0; ks < 2; ++ks) {
                const short* krow = &Ks[(mt * 16 + l16) * 68];
                short4 lo = *(const short4*)&krow[4 * g + 32 * ks];
                short4 hi = *(const short4*)&krow[4 * g + 16 + 32 * ks];
                acc = __builtin_amdgcn_mfma_f32_16x16x32_bf16(mk_frag(lo, hi), qf[ks], acc, 0, 0, 0);
            }
            st[mt] = acc;
        }
        __builtin_amdgcn_s_setprio(0);

        // ---- online softmax: lane owns q = l16; keys 16*mt + 4g + reg ----
        float s8[8];
        #pragma unroll
        for (int mt = 0; mt < 2; ++mt)
            #pragma unroll
            for (int r = 0; r < 4; ++r)
                s8[mt * 4 + r] = st[mt][r] * 0.125f;
        float tm = s8[0];
        #pragma unroll
        for (int j = 1; j < 8; ++j) tm = fmaxf(tm, s8[j]);
        tm = fmaxf(tm, __shfl_xor(tm, 16));
        tm = fmaxf(tm, __shfl_xor(tm, 32));
        float mnew = fmaxf(mrun, tm);
        float c = __expf(mrun - mnew);
        mrun = mnew;
        float ps = 0.f;
        short pb[8];
        #pragma unroll
        for (int j = 0; j < 8; ++j) {
            float p = __expf(s8[j] - mrun);
            ps += p;
            pb[j] = f2bf(p);
        }
        ps += __shfl_xor(ps, 16);
        ps += __shfl_xor(ps, 32);
        lrun = lrun * c + ps;
        #pragma unroll
        for (int dt = 0; dt < 4; ++dt)
            #pragma unroll
            for (int r = 0; r < 4; ++r)
                oa[dt][r] *= c;
        s16x8_t pt;
        #pragma unroll
        for (int j = 0; j < 8; ++j) pt[j] = pb[j];
        bf16x8_t pf = __builtin_bit_cast(bf16x8_t, pt);

        // ---- O^T += V^T @ P^T : 4 dh-tiles, K-dim = 32 keys ----
        __builtin_amdgcn_s_setprio(1);
        #pragma unroll
        for (int dt = 0; dt < 4; ++dt) {
            const short* vrow = &Vt[(dt * 16 + l16) * 36];
            short4 lo = *(const short4*)&vrow[4 * g];
            short4 hi = *(const short4*)&vrow[16 + 4 * g];
            oa[dt] = __builtin_amdgcn_mfma_f32_16x16x32_bf16(mk_frag(lo, hi), pf, oa[dt], 0, 0, 0);
        }
        __builtin_amdgcn_s_setprio(0);
    }

    // ---- epilogue: O^T -> O via per-wave LDS bounce, coalesced bf16 write ----
    float inv = 1.f / lrun;
    #pragma unroll
    for (int dt = 0; dt < 4; ++dt)
        #pragma unroll
        for (int r = 0; r < 4; ++r)
            Ol[(w * 16 + l16) * 68 + 16 * dt + 4 * g + r] = oa[dt][r] * inv;
    int qr = lane >> 2, cc = lane & 3;
    const float* orow = &Ol[(w * 16 + qr) * 68 + cc * 16];
    s16x8_t s0, s1;
    #pragma unroll
    for (int j = 0; j < 8; ++j) { s0[j] = f2bf(orow[j]); s1[j] = f2bf(orow[8 + j]); }
    size_t gb = (size_t)(b * SEQ + qb * 32 + w * 16 + qr) * E + h * 64 + cc * 16;
    *(s16x8_t*)&out[gb] = s0;
    *(s16x8_t*)&out[gb + 8] = s1;
}

extern "C" void kernel_launch(void* const* d_in, const int* in_sizes, int n_in,
                              void* d_out, int out_size, void* d_ws, size_t ws_size,
                              hipStream_t stream) {
    const int*   idx = (const int*)d_in[0];
    // d_in[1] = attention_mask (bool) — unused: mask is frame(key) <= frame(query), computed analytically
    const float* ce  = (const float*)d_in[2];
    const float* se  = (const float*)d_in[3];
    const float* tp  = (const float*)d_in[4];
    const float* jp  = (const float*)d_in[5];
    const float* ipw = (const float*)d_in[6];
    const float* ipb = (const float*)d_in[7];
    const float* ow  = (const float*)d_in[8];
    const float* ob  = (const float*)d_in[9];
    const float* l1g = (const float*)d_in[10];
    const float* l1b = (const float*)d_in[11];
    const float* w1  = (const float*)d_in[12];
    const float* b1  = (const float*)d_in[13];
    const float* w2  = (const float*)d_in[14];
    const float* b2  = (const float*)d_in[15];
    const float* l2g = (const float*)d_in[16];
    const float* l2b = (const float*)d_in[17];

    float* x = (float*)d_out;                              // residual stream (fp32)
    // workspace layout (26.3 MB total):
    short* y_bf   = (short*)d_ws;                          // [4096][512]  bf16, 4 MB
    short* qkv_bf = (short*)((char*)d_ws + (4u << 20));    // [4096][1536] bf16 (12 MB)
    short* h_bf   = qkv_bf;                                // [4096][2048] bf16 overlays qkv (16 MB)
    short* wb     = (short*)((char*)d_ws + (20u << 20));   // per-layer bf16 weights, 6.3 MB
    short* wip = wb;                  // [1536][512]
    short* wob = wb + 786432;         // [512][512]
    short* w1b = wb + 1048576;        // [2048][512]
    short* w2b = wb + 2097152;        // [512][2048]

    embed_kernel<<<2048, 256, 0, stream>>>(idx, ce, se, tp, jp, x);

    for (int l = 0; l < NLAYER; ++l) {
        cast4_kernel<<<1536, 256, 0, stream>>>(
            ipw + (size_t)l * 786432, ow + (size_t)l * 262144,
            w1 + (size_t)l * 1048576, w2 + (size_t)l * 1048576, wb);
        ln_kernel<<<1024, 256, 0, stream>>>(x, y_bf, l1g + l * E, l1b + l * E);
        gemm_mfma_kernel<0><<<32 * 12, 256, 0, stream>>>(
            y_bf, wip, ipb + (size_t)l * 1536, nullptr, qkv_bf, 1536, 512);
        attn_mfma_kernel<<<1024, 128, 0, stream>>>(qkv_bf, y_bf);
        gemm_mfma_kernel<1><<<32 * 4, 256, 0, stream>>>(
            y_bf, wob, ob + (size_t)l * E, x, x, 512, 512);
        ln_kernel<<<1024, 256, 0, stream>>>(x, y_bf, l2g + l * E, l2b + l * E);
        gemm_mfma_kernel<2><<<32 * 16, 256, 0, stream>>>(
            y_bf, w1b, b1 + (size_t)l * DFF, nullptr, h_bf, 2048, 512);
        gemm_mfma_kernel<1><<<32 * 4, 256, 0, stream>>>(
            h_bf, w2b, b2 + (size_t)l * E, x, x, 512, 2048);
    }
}

// Round 7
// 1225.415 us; speedup vs baseline: 9.0116x; 1.0043x over previous
//
#include <hip/hip_runtime.h>
#include <hip/hip_bf16.h>
#include <math.h>

#define E 512
#define H_HEADS 8
#define DH 64
#define NLAYER 6
#define DFF 2048
#define SEQ 2048      // T*V
#define NB 2          // batch
#define M_TOK (NB*SEQ) // 4096 rows

typedef float f32x4_t __attribute__((ext_vector_type(4)));
typedef __bf16 bf16x8_t __attribute__((ext_vector_type(8)));
typedef short s16x8_t __attribute__((ext_vector_type(8)));

// float -> bf16 bits, round-to-nearest-even
__device__ __forceinline__ short f2bf(float f) {
    union { float f; unsigned u; } v; v.f = f;
    unsigned r = v.u + 0x7FFFu + ((v.u >> 16) & 1u);
    return (short)(r >> 16);
}
__device__ __forceinline__ float bf2f(short s) {
    union { unsigned u; float f; } v; v.u = ((unsigned)(unsigned short)s) << 16;
    return v.f;
}

__device__ __forceinline__ bf16x8_t mk_frag(short4 lo, short4 hi) {
    s16x8_t t;
    t[0] = lo.x; t[1] = lo.y; t[2] = lo.z; t[3] = lo.w;
    t[4] = hi.x; t[5] = hi.y; t[6] = hi.z; t[7] = hi.w;
    return __builtin_bit_cast(bf16x8_t, t);
}

__device__ __forceinline__ void gload16(const void* g, void* l) {
    __builtin_amdgcn_global_load_lds(
        (const __attribute__((address_space(1))) void*)g,
        (__attribute__((address_space(3))) void*)l, 16, 0, 0);
}

// ---------------- embedding: x = code_emb[idx] + stage + time_pos + joint_pos ----------------
__global__ __launch_bounds__(256) void embed_kernel(
    const int* __restrict__ idx, const float* __restrict__ ce,
    const float* __restrict__ se, const float* __restrict__ tp,
    const float* __restrict__ jp, float* __restrict__ x)
{
    int i = blockIdx.x * 256 + threadIdx.x;   // float4 index, total 524288
    int e4 = i & 127;                          // E/4 = 128
    int row = i >> 7;                          // 0..4095  = b*2048 + t*32 + v
    int v = row & 31;
    int t = (row >> 5) & 63;
    int code = idx[row];
    const float4* ce4 = (const float4*)ce;
    const float4* se4 = (const float4*)se;
    const float4* tp4 = (const float4*)tp;
    const float4* jp4 = (const float4*)jp;
    float4 a = ce4[code * 128 + e4];
    float4 b = se4[e4];
    float4 c = tp4[t * 128 + e4];
    float4 d = jp4[v * 128 + e4];
    float4 o;
    o.x = a.x + b.x + c.x + d.x;
    o.y = a.y + b.y + c.y + d.y;
    o.z = a.z + b.z + c.z + d.z;
    o.w = a.w + b.w + c.w + d.w;
    ((float4*)x)[i] = o;
}

// ---------------- weight cast: one layer's 4 weight mats fp32 -> bf16 ----------------
__global__ __launch_bounds__(256) void cast4_kernel(
    const float* __restrict__ w0, const float* __restrict__ w1,
    const float* __restrict__ w2, const float* __restrict__ w3,
    short* __restrict__ o)
{
    int i = blockIdx.x * 256 + threadIdx.x;   // chunk of 8
    const float* src; int off;
    if (i < 98304)       { src = w0; off = i; }
    else if (i < 131072) { src = w1; off = i - 98304; }
    else if (i < 262144) { src = w2; off = i - 131072; }
    else                 { src = w3; off = i - 262144; }
    float4 a = ((const float4*)src)[off * 2];
    float4 b = ((const float4*)src)[off * 2 + 1];
    s16x8_t s;
    s[0] = f2bf(a.x); s[1] = f2bf(a.y); s[2] = f2bf(a.z); s[3] = f2bf(a.w);
    s[4] = f2bf(b.x); s[5] = f2bf(b.y); s[6] = f2bf(b.z); s[7] = f2bf(b.w);
    *(s16x8_t*)&o[(size_t)i * 8] = s;
}

// ---------------- LayerNorm: one wave per row of 512, bf16 output ----------------
__global__ __launch_bounds__(256) void ln_kernel(
    const float* __restrict__ x, short* __restrict__ y,
    const float* __restrict__ g, const float* __restrict__ b)
{
    int wave = threadIdx.x >> 6;
    int lane = threadIdx.x & 63;
    int row = blockIdx.x * 4 + wave;
    const float4* xr = (const float4*)(x + (size_t)row * E);
    float4 v0 = xr[lane];
    float4 v1 = xr[lane + 64];
    float s  = v0.x + v0.y + v0.z + v0.w + v1.x + v1.y + v1.z + v1.w;
    float ss = v0.x*v0.x + v0.y*v0.y + v0.z*v0.z + v0.w*v0.w
             + v1.x*v1.x + v1.y*v1.y + v1.z*v1.z + v1.w*v1.w;
    #pragma unroll
    for (int off = 32; off; off >>= 1) {
        s  += __shfl_xor(s, off, 64);
        ss += __shfl_xor(ss, off, 64);
    }
    float mu = s * (1.f / E);
    float var = ss * (1.f / E) - mu * mu;
    float rs = rsqrtf(var + 1e-5f);
    const float4* g4 = (const float4*)g;
    const float4* b4 = (const float4*)b;
    float4 gg = g4[lane], bb = b4[lane];
    short4 o;
    o.x = f2bf((v0.x - mu) * rs * gg.x + bb.x);
    o.y = f2bf((v0.y - mu) * rs * gg.y + bb.y);
    o.z = f2bf((v0.z - mu) * rs * gg.z + bb.z);
    o.w = f2bf((v0.w - mu) * rs * gg.w + bb.w);
    *(short4*)&y[(size_t)row * E + lane * 4] = o;
    gg = g4[lane + 64]; bb = b4[lane + 64];
    o.x = f2bf((v1.x - mu) * rs * gg.x + bb.x);
    o.y = f2bf((v1.y - mu) * rs * gg.y + bb.y);
    o.z = f2bf((v1.z - mu) * rs * gg.z + bb.z);
    o.w = f2bf((v1.w - mu) * rs * gg.w + bb.w);
    *(short4*)&y[(size_t)row * E + 256 + lane * 4] = o;
}

// ---------------- bf16 MFMA GEMM (m97 structure, unchanged from round 5) ----------------
template<int MODE>
__global__ __launch_bounds__(256) void gemm_mfma_kernel(
    const short* __restrict__ A, const short* __restrict__ W,
    const float* __restrict__ bias, const float* __restrict__ res,
    void* __restrict__ out, int N, int K)
{
    __shared__ short As[128 * 64];
    __shared__ short Bs[128 * 64];
    int nb = N >> 7;
    int bx = blockIdx.x % nb;
    int by = blockIdx.x / nb;
    int tid = threadIdx.x;
    int lane = tid & 63, g = lane >> 4, l16 = lane & 15;
    int w = tid >> 6, wm = w >> 1, wn = w & 1;
    int wbase = tid & 192;

    f32x4_t acc[4][4] = {};
    const short* Ab = A + (size_t)(by * 128) * K;
    const short* Wb = W + (size_t)(bx * 128) * K;

    for (int k0 = 0; k0 < K; k0 += 64) {
        __syncthreads();
        #pragma unroll
        for (int u = 0; u < 4; ++u) {
            int c = u * 256 + tid;
            int row = c >> 3, c8 = c & 7;
            gload16(Ab + (size_t)row * K + k0 + c8 * 8, As + (u * 256 + wbase) * 8);
            gload16(Wb + (size_t)row * K + k0 + c8 * 8, Bs + (u * 256 + wbase) * 8);
        }
        __syncthreads();
        #pragma unroll
        for (int ks = 0; ks < 2; ++ks) {
            bf16x8_t af[4], bf[4];
            #pragma unroll
            for (int i = 0; i < 4; ++i) {
                af[i] = *(const bf16x8_t*)&As[(wm * 64 + i * 16 + l16) * 64 + ks * 32 + g * 8];
                bf[i] = *(const bf16x8_t*)&Bs[(wn * 64 + i * 16 + l16) * 64 + ks * 32 + g * 8];
            }
            #pragma unroll
            for (int mi = 0; mi < 4; ++mi)
                #pragma unroll
                for (int ni = 0; ni < 4; ++ni)
                    acc[mi][ni] = __builtin_amdgcn_mfma_f32_16x16x32_bf16(
                        af[mi], bf[ni], acc[mi][ni], 0, 0, 0);
        }
    }

    int gm0 = by * 128 + wm * 64;
    int gn0 = bx * 128 + wn * 64;
    #pragma unroll
    for (int ni = 0; ni < 4; ++ni) {
        int gn = gn0 + ni * 16 + l16;
        float bv = bias[gn];
        #pragma unroll
        for (int mi = 0; mi < 4; ++mi) {
            #pragma unroll
            for (int r = 0; r < 4; ++r) {
                int gm = gm0 + mi * 16 + g * 4 + r;
                float v = acc[mi][ni][r] + bv;
                if (MODE == 2) v = 0.5f * v * (1.f + erff(v * 0.70710678118f));
                if (MODE == 1) {
                    v += res[(size_t)gm * N + gn];
                    ((float*)out)[(size_t)gm * N + gn] = v;
                } else {
                    ((short*)out)[(size_t)gm * N + gn] = f2bf(v);
                }
            }
        }
    }
}

// ---------------- MFMA bf16 flash attention, split-K (flash-decoding) ----------------
// Grid = 64 qb x 4 chunks x 16 (b,h) = 4096 blocks, 128 threads (2 waves x 16 q-rows).
// Chunk c covers keys [c*512, min((c+1)*512, (qb+1)*32)); invalid chunks exit.
// Each block writes unnormalized partial O (bf16) + per-row (m, l) at compact index
// cidx = bh*160 + (a+1)*(8a+r) + c  where qb = 16a+r.  Combine kernel merges.
// Fragment maps identical to the round-2/3 verified kernel.
__global__ __launch_bounds__(128) void attn_mfma_kernel(
    const short* __restrict__ qkv, short* __restrict__ opart,
    float* __restrict__ mlbuf)
{
    __shared__ __align__(16) char smem[13312];
    short* Qs = (short*)smem;              // [32][68] bf16
    short* Ks = (short*)(smem + 4352);     // [32][68] bf16
    short* Vt = (short*)(smem + 8704);     // [64][36] bf16
    float* Ol = (float*)smem;              // epilogue overlay [32][68] f32 (8704 B)

    int bid = blockIdx.x;
    int c   = bid & 3;
    int qb  = 63 - ((bid >> 2) & 63);      // longest-first
    int bh  = bid >> 8;                    // 0..15 = b*8+h
    if (c * 16 > qb) return;               // chunk beyond causal bound
    int h = bh & 7, b = bh >> 3;
    int a_ = qb >> 4, r_ = qb & 15;
    int cidx = bh * 160 + (a_ + 1) * (8 * a_ + r_) + c;

    int tid  = threadIdx.x;
    int w    = tid >> 6;
    int lane = tid & 63;
    int g    = lane >> 4;
    int l16  = lane & 15;

    const short* base = qkv + (size_t)(b * SEQ) * 1536;

    // ---- stage Q block [32 q][64 dh] ----
    #pragma unroll
    for (int u = 0; u < 4; ++u) {
        int f = tid + 128 * u;             // 0..511 short4-chunks
        int qr = f >> 4, c4 = f & 15;
        short4 v = *(const short4*)(base + (size_t)(qb * 32 + qr) * 1536 + h * 64 + c4 * 4);
        *(short4*)&Qs[qr * 68 + c4 * 4] = v;
    }

    int kstart = c * 512;
    int kcend  = min((qb + 1) * 32, kstart + 512);

    // ---- prefetch first tile's K/V into registers ----
    short4 kreg[4], vreg[4];
    #pragma unroll
    for (int u = 0; u < 4; ++u) {
        int f = tid + 128 * u;
        int key = f >> 4, c4 = f & 15;
        const short* row = base + (size_t)(kstart + key) * 1536 + h * 64;
        kreg[u] = *(const short4*)(row + 512 + c4 * 4);
        vreg[u] = *(const short4*)(row + 1024 + c4 * 4);
    }
    __syncthreads();

    // per-wave Q^T B-fragments: n = q = l16, k = dh = 4g + (j&3) + 16*(j>>2) + 32*ks
    bf16x8_t qf[2];
    #pragma unroll
    for (int ks = 0; ks < 2; ++ks) {
        const short* qrow = &Qs[(w * 16 + l16) * 68];
        short4 lo = *(const short4*)&qrow[4 * g + 32 * ks];
        short4 hi = *(const short4*)&qrow[4 * g + 16 + 32 * ks];
        qf[ks] = mk_frag(lo, hi);
    }

    f32x4_t oa[4] = {};
    float mrun = -1e30f, lrun = 0.f;

    for (int kt = kstart; kt < kcend; kt += 32) {
        __syncthreads();
        // ---- write prefetched K/V regs -> LDS (K row-major, V transposed) ----
        #pragma unroll
        for (int u = 0; u < 4; ++u) {
            int f = tid + 128 * u;
            int key = f >> 4, c4 = f & 15;
            *(short4*)&Ks[key * 68 + c4 * 4] = kreg[u];
            Vt[(c4 * 4 + 0) * 36 + key] = vreg[u].x;
            Vt[(c4 * 4 + 1) * 36 + key] = vreg[u].y;
            Vt[(c4 * 4 + 2) * 36 + key] = vreg[u].z;
            Vt[(c4 * 4 + 3) * 36 + key] = vreg[u].w;
        }
        // ---- issue next tile's global loads ----
        if (kt + 32 < kcend) {
            #pragma unroll
            for (int u = 0; u < 4; ++u) {
                int f = tid + 128 * u;
                int key = f >> 4, c4 = f & 15;
                const short* row = base + (size_t)(kt + 32 + key) * 1536 + h * 64;
                kreg[u] = *(const short4*)(row + 512 + c4 * 4);
                vreg[u] = *(const short4*)(row + 1024 + c4 * 4);
            }
        }
        __syncthreads();

        // ---- S^T[key][q] = K @ Q^T ----
        f32x4_t st[2];
        __builtin_amdgcn_s_setprio(1);
        #pragma unroll
        for (int mt = 0; mt < 2; ++mt) {
            f32x4_t acc = {0.f, 0.f, 0.f, 0.f};
            #pragma unroll
            for (int ks = 0; ks < 2; ++ks) {
                const short* krow = &Ks[(mt * 16 + l16) * 68];
                short4 lo = *(const short4*)&krow[4 * g + 32 * ks];
                short4 hi = *(const short4*)&krow[4 * g + 16 + 32 * ks];
                acc = __builtin_amdgcn_mfma_f32_16x16x32_bf16(mk_frag(lo, hi), qf[ks], acc, 0, 0, 0);
            }
            st[mt] = acc;
        }
        __builtin_amdgcn_s_setprio(0);

        // ---- online softmax: lane owns q = l16; keys 16*mt + 4g + reg ----
        float s8[8];
        #pragma unroll
        for (int mt = 0; mt < 2; ++mt)
            #pragma unroll
            for (int r = 0; r < 4; ++r)
                s8[mt * 4 + r] = st[mt][r] * 0.125f;
        float tm = s8[0];
        #pragma unroll
        for (int j = 1; j < 8; ++j) tm = fmaxf(tm, s8[j]);
        tm = fmaxf(tm, __shfl_xor(tm, 16));
        tm = fmaxf(tm, __shfl_xor(tm, 32));
        float mnew = fmaxf(mrun, tm);
        float cf = __expf(mrun - mnew);
        mrun = mnew;
        float ps = 0.f;
        short pb[8];
        #pragma unroll
        for (int j = 0; j < 8; ++j) {
            float p = __expf(s8[j] - mrun);
            ps += p;
            pb[j] = f2bf(p);
        }
        ps += __shfl_xor(ps, 16);
        ps += __shfl_xor(ps, 32);
        lrun = lrun * cf + ps;
        #pragma unroll
        for (int dt = 0; dt < 4; ++dt)
            #pragma unroll
            for (int r = 0; r < 4; ++r)
                oa[dt][r] *= cf;
        s16x8_t pt;
        #pragma unroll
        for (int j = 0; j < 8; ++j) pt[j] = pb[j];
        bf16x8_t pf = __builtin_bit_cast(bf16x8_t, pt);

        // ---- O^T += V^T @ P^T ----
        __builtin_amdgcn_s_setprio(1);
        #pragma unroll
        for (int dt = 0; dt < 4; ++dt) {
            const short* vrow = &Vt[(dt * 16 + l16) * 36];
            short4 lo = *(const short4*)&vrow[4 * g];
            short4 hi = *(const short4*)&vrow[16 + 4 * g];
            oa[dt] = __builtin_amdgcn_mfma_f32_16x16x32_bf16(mk_frag(lo, hi), pf, oa[dt], 0, 0, 0);
        }
        __builtin_amdgcn_s_setprio(0);
    }

    // ---- epilogue: unnormalized O^T -> [q][dh] via LDS overlay, write bf16 partial + ml ----
    __syncthreads();                        // Ks/Vt reads done in both waves (Ol aliases)
    #pragma unroll
    for (int dt = 0; dt < 4; ++dt)
        #pragma unroll
        for (int r = 0; r < 4; ++r)
            Ol[(w * 16 + l16) * 68 + 16 * dt + 4 * g + r] = oa[dt][r];
    if (g == 0) {
        mlbuf[cidx * 64 + w * 16 + l16] = mrun;
        mlbuf[cidx * 64 + 32 + w * 16 + l16] = lrun;
    }
    int q = tid >> 2, d0 = (tid & 3) * 16;
    const float* orow = &Ol[q * 68 + d0];   // same-wave data (q matches wave range)
    s16x8_t s0, s1;
    #pragma unroll
    for (int j = 0; j < 8; ++j) { s0[j] = f2bf(orow[j]); s1[j] = f2bf(orow[8 + j]); }
    size_t ob = (size_t)cidx * 2048 + q * 64 + d0;
    *(s16x8_t*)&opart[ob] = s0;
    *(s16x8_t*)&opart[ob + 8] = s1;
}

// ---------------- split-K combine: exp-weighted merge of partials -> y bf16 ----------------
// Grid = 16 bh x 64 qb = 1024 blocks, 128 threads. Thread: q = t>>2, 16 dh cols.
__global__ __launch_bounds__(128) void attn_combine_kernel(
    const short* __restrict__ opart, const float* __restrict__ mlbuf,
    short* __restrict__ y)
{
    int bid = blockIdx.x;
    int qb = bid & 63, bh = bid >> 6;
    int h = bh & 7, b = bh >> 3;
    int a_ = qb >> 4, r_ = qb & 15;
    int cbase = bh * 160 + (a_ + 1) * (8 * a_ + r_);
    int nc = a_ + 1;
    int t = threadIdx.x;
    int q = t >> 2, d0 = (t & 3) * 16;

    float M = -1e30f;
    #pragma unroll
    for (int cc = 0; cc < 4; ++cc)
        if (cc < nc) M = fmaxf(M, mlbuf[(cbase + cc) * 64 + q]);
    float L = 0.f;
    float acc[16] = {};
    #pragma unroll
    for (int cc = 0; cc < 4; ++cc) {
        if (cc < nc) {
            float mv = mlbuf[(cbase + cc) * 64 + q];
            float lv = mlbuf[(cbase + cc) * 64 + 32 + q];
            float wgt = __expf(mv - M);
            L += wgt * lv;
            const short* op = &opart[(size_t)(cbase + cc) * 2048 + q * 64 + d0];
            s16x8_t v0 = *(const s16x8_t*)op;
            s16x8_t v1 = *(const s16x8_t*)(op + 8);
            #pragma unroll
            for (int j = 0; j < 8; ++j) {
                acc[j]     += wgt * bf2f(v0[j]);
                acc[8 + j] += wgt * bf2f(v1[j]);
            }
        }
    }
    float inv = 1.f / L;
    s16x8_t o0, o1;
    #pragma unroll
    for (int j = 0; j < 8; ++j) { o0[j] = f2bf(acc[j] * inv); o1[j] = f2bf(acc[8 + j] * inv); }
    size_t gb = (size_t)(b * SEQ + qb * 32 + q) * E + h * 64 + d0;
    *(s16x8_t*)&y[gb] = o0;
    *(s16x8_t*)&y[gb + 8] = o1;
}

extern "C" void kernel_launch(void* const* d_in, const int* in_sizes, int n_in,
                              void* d_out, int out_size, void* d_ws, size_t ws_size,
                              hipStream_t stream) {
    const int*   idx = (const int*)d_in[0];
    // d_in[1] = attention_mask (bool) — unused: mask is frame(key) <= frame(query), computed analytically
    const float* ce  = (const float*)d_in[2];
    const float* se  = (const float*)d_in[3];
    const float* tp  = (const float*)d_in[4];
    const float* jp  = (const float*)d_in[5];
    const float* ipw = (const float*)d_in[6];
    const float* ipb = (const float*)d_in[7];
    const float* ow  = (const float*)d_in[8];
    const float* ob  = (const float*)d_in[9];
    const float* l1g = (const float*)d_in[10];
    const float* l1b = (const float*)d_in[11];
    const float* w1  = (const float*)d_in[12];
    const float* b1  = (const float*)d_in[13];
    const float* w2  = (const float*)d_in[14];
    const float* b2  = (const float*)d_in[15];
    const float* l2g = (const float*)d_in[16];
    const float* l2b = (const float*)d_in[17];

    float* x = (float*)d_out;                              // residual stream (fp32)
    // workspace layout (37.7 MB total):
    short* y_bf   = (short*)d_ws;                          // [4096][512]  bf16, 4 MiB
    short* qkv_bf = (short*)((char*)d_ws + (4u << 20));    // [4096][1536] bf16 (12 MiB)
    short* h_bf   = qkv_bf;                                // [4096][2048] bf16 overlays qkv (16 MiB)
    short* wb     = (short*)((char*)d_ws + (20u << 20));   // per-layer bf16 weights, 6.3 MiB
    short* wip = wb;                  // [1536][512]
    short* wob = wb + 786432;         // [512][512]
    short* w1b = wb + 1048576;        // [2048][512]
    short* w2b = wb + 2097152;        // [512][2048]
    short* opart = (short*)((char*)d_ws + (27u << 20));    // 2560 x [32][64] bf16, 10 MiB
    float* mlbuf = (float*)((char*)d_ws + (37u << 20));    // 2560 x [64] f32, 0.64 MiB

    embed_kernel<<<2048, 256, 0, stream>>>(idx, ce, se, tp, jp, x);

    for (int l = 0; l < NLAYER; ++l) {
        cast4_kernel<<<1536, 256, 0, stream>>>(
            ipw + (size_t)l * 786432, ow + (size_t)l * 262144,
            w1 + (size_t)l * 1048576, w2 + (size_t)l * 1048576, wb);
        ln_kernel<<<1024, 256, 0, stream>>>(x, y_bf, l1g + l * E, l1b + l * E);
        gemm_mfma_kernel<0><<<32 * 12, 256, 0, stream>>>(
            y_bf, wip, ipb + (size_t)l * 1536, nullptr, qkv_bf, 1536, 512);
        attn_mfma_kernel<<<4096, 128, 0, stream>>>(qkv_bf, opart, mlbuf);
        attn_combine_kernel<<<1024, 128, 0, stream>>>(opart, mlbuf, y_bf);
        gemm_mfma_kernel<1><<<32 * 4, 256, 0, stream>>>(
            y_bf, wob, ob + (size_t)l * E, x, x, 512, 512);
        ln_kernel<<<1024, 256, 0, stream>>>(x, y_bf, l2g + l * E, l2b + l * E);
        gemm_mfma_kernel<2><<<32 * 16, 256, 0, stream>>>(
            y_bf, w1b, b1 + (size_t)l * DFF, nullptr, h_bf, 2048, 512);
        gemm_mfma_kernel<1><<<32 * 4, 256, 0, stream>>>(
            h_bf, w2b, b2 + (size_t)l * E, x, x, 512, 2048);
    }
}